// Round 1
// 178.165 us; speedup vs baseline: 1.0064x; 1.0064x over previous
//
#include <hip/hip_runtime.h>
#include <cstdint>
#include <cstddef>

#define MROWS 24000
#define NCOLS 1024
#define KDIM  768
#define MT 188          // ceil(24000/128) m-tiles (padded to 24064 rows)
#define KT 48           // 768/16 k-tiles
#define NT 4            // 1024/256 n-tiles

typedef _Float16 f16x8  __attribute__((ext_vector_type(8)));
typedef float    f32x16 __attribute__((ext_vector_type(16)));

typedef __attribute__((address_space(1))) void as1_void;
typedef __attribute__((address_space(3))) void as3_void;

// ---- workspace layout (bytes) ----
#define A_BYTES   (188ull*48*8192)            // 73,924,608
#define B_OFF     A_BYTES
#define B_BYTES   (4ull*48*16384)             // 3,145,728
#define CH_OFF    (A_BYTES + B_BYTES)         // 77,070,336
#define PART_OFF  (CH_OFF + 4096)             // 77,074,432
#define WS_NEED   (PART_OFF + 24064ull*4*8)   // 77,844,480

// ---------------- conv A: embed -> tiled fp16 hi/lo ----------------
__global__ void k_tile_A(const float* __restrict__ E, _Float16* __restrict__ Aw) {
  int bid = blockIdx.x;            // mt*48 + kt
  int mt = bid / 48, kt = bid % 48;
  int t = threadIdx.x;             // 256
  int r = t >> 1, p = t & 1;
  int row = mt * 128 + r;
  __shared__ _Float16 lh[2][128][8];
  __shared__ _Float16 ll[2][128][8];
  float x[8];
  if (row < MROWS) {
    const float4* s4 = (const float4*)(E + (size_t)row * KDIM + kt * 16 + p * 8);
    float4 v0 = s4[0], v1 = s4[1];
    x[0]=v0.x; x[1]=v0.y; x[2]=v0.z; x[3]=v0.w; x[4]=v1.x; x[5]=v1.y; x[6]=v1.z; x[7]=v1.w;
  } else {
#pragma unroll
    for (int e = 0; e < 8; ++e) x[e] = 0.f;
  }
#pragma unroll
  for (int e = 0; e < 8; ++e) {
    _Float16 h = (_Float16)x[e];
    lh[p][r][e] = h;
    ll[p][r][e] = (_Float16)(x[e] - (float)h);
  }
  __syncthreads();
  const uint4* sh = (const uint4*)&lh[0][0][0];
  const uint4* sl = (const uint4*)&ll[0][0][0];
  uint4* dst = (uint4*)(Aw + (size_t)bid * 4096);   // 8192 B per tile
  dst[t]       = sh[t];    // h region: 256 chunks
  dst[256 + t] = sl[t];    // l region
}

// ---------------- conv B: centers -> tiled fp16 hi/lo ----------------
__global__ void k_tile_B(const float* __restrict__ C, _Float16* __restrict__ Bw) {
  int bid = blockIdx.x;            // nt*48 + kt
  int nt = bid / 48, kt = bid % 48;
  int t = threadIdx.x;             // 512
  int c = t >> 1, p = t & 1;
  __shared__ _Float16 lh[2][256][8];
  __shared__ _Float16 ll[2][256][8];
  const float4* s4 = (const float4*)(C + (size_t)(nt * 256 + c) * KDIM + kt * 16 + p * 8);
  float4 v0 = s4[0], v1 = s4[1];
  float x[8] = {v0.x, v0.y, v0.z, v0.w, v1.x, v1.y, v1.z, v1.w};
#pragma unroll
  for (int e = 0; e < 8; ++e) {
    _Float16 h = (_Float16)x[e];
    lh[p][c][e] = h;
    ll[p][c][e] = (_Float16)(x[e] - (float)h);
  }
  __syncthreads();
  const uint4* sh = (const uint4*)&lh[0][0][0];
  const uint4* sl = (const uint4*)&ll[0][0][0];
  uint4* dst = (uint4*)(Bw + (size_t)bid * 8192);   // 16384 B per tile
  dst[t]       = sh[t];    // h region: 512 chunks
  dst[512 + t] = sl[t];    // l region
}

// ---------------- 0.5*||c||^2 ----------------
__global__ void k_chalf(const float* __restrict__ C, float* __restrict__ ch) {
  int c = blockIdx.x, t = threadIdx.x;   // 256
  const float* src = C + (size_t)c * KDIM;
  float sq = 0.f;
#pragma unroll
  for (int i = 0; i < 3; ++i) {
    float x = src[t + i * 256];
    sq = fmaf(x, x, sq);
  }
#pragma unroll
  for (int m = 1; m < 64; m <<= 1) sq += __shfl_xor(sq, m, 64);
  __shared__ float part[4];
  if ((t & 63) == 0) part[t >> 6] = sq;
  __syncthreads();
  if (t == 0) ch[c] = 0.5f * ((part[0] + part[1]) + (part[2] + part[3]));
}

// ---------------- fused GEMM: 3-deep pipeline, counted vmcnt, 4 waves ----------------
// Block tile 128x256, 4 waves (2x2), wave tile 64x128, acc[2][4] 32x32 frags.
// Triple-buffered LDS (24KB each): K-tile j lives in buf j%3; during K-tile j we
// issue tile j+2's 6 global_load_lds into buf (j+2)%3 (freed by the barrier at
// K-tile j entry). Barrier at each K-tile entry = s_waitcnt vmcnt(6); s_barrier:
// waits own 6 oldest (tile j's) loads, leaves tile j+1's 6 in flight.
__global__ __launch_bounds__(256, 2) void k_gemm(
    const _Float16* __restrict__ Aw, const _Float16* __restrict__ Bw,
    const float* __restrict__ ch, uint2* __restrict__ part) {
  __shared__ __align__(16) char smem[3][24576];   // per buf: [A 8KB][B 16KB]
  __shared__ float red_v[2][128];
  __shared__ int   red_i[2][128];

  const int bid0 = blockIdx.x;                  // 0..751
  const int swz = (bid0 & 7) * 94 + (bid0 >> 3);  // 752 = 8*94, bijective XCD swizzle
  const int nt = swz / MT, mt = swz % MT;

  const int tid = threadIdx.x, lane = tid & 63, wid = tid >> 6;  // 4 waves
  const int wm = wid >> 1, wn = wid & 1;        // 2x2 wave grid, wave tile 64x128
  const int lo5 = lane & 31, p = lane >> 5;

  const char* Ab = (const char*)Aw + (size_t)mt * (48 * 8192);
  const char* Bb = (const char*)Bw + (size_t)nt * (48 * 16384);

  auto stage = [&](char* sb, int kt, int half) {
    const char* ga = Ab + kt * 8192;
    const char* gb = Bb + kt * 16384;
    if (half == 0) {
      __builtin_amdgcn_global_load_lds((as1_void*)(ga + tid * 16),        (as3_void*)(sb + tid * 16),         16, 0, 0);
      __builtin_amdgcn_global_load_lds((as1_void*)(ga + 4096 + tid * 16), (as3_void*)(sb + 4096 + tid * 16),  16, 0, 0);
      __builtin_amdgcn_global_load_lds((as1_void*)(gb + tid * 16),        (as3_void*)(sb + 8192 + tid * 16),  16, 0, 0);
    } else {
      __builtin_amdgcn_global_load_lds((as1_void*)(gb + 4096 + tid * 16),  (as3_void*)(sb + 12288 + tid * 16), 16, 0, 0);
      __builtin_amdgcn_global_load_lds((as1_void*)(gb + 8192 + tid * 16),  (as3_void*)(sb + 16384 + tid * 16), 16, 0, 0);
      __builtin_amdgcn_global_load_lds((as1_void*)(gb + 12288 + tid * 16), (as3_void*)(sb + 20480 + tid * 16), 16, 0, 0);
    }
  };

  f32x16 acc[2][4] = {};

  const int offA0 = p * 2048 + (wm * 64 + lo5) * 16;   // + mi*512
  const int offB0 = p * 4096 + (wn * 128 + lo5) * 16;  // + ni*512

  auto ktile = [&](const char* rb, char* wb, int jstage) {
    // ---- phase 0: A frags (all) + B frags ni={0,1}; stage half 0; 12 MFMA ----
    f16x8 a[2][2], b[2][2];
#pragma unroll
    for (int mi = 0; mi < 2; ++mi)
#pragma unroll
      for (int pl = 0; pl < 2; ++pl)
        a[mi][pl] = *(const f16x8*)(rb + pl * 4096 + offA0 + mi * 512);
#pragma unroll
    for (int ni = 0; ni < 2; ++ni)
#pragma unroll
      for (int pl = 0; pl < 2; ++pl)
        b[ni][pl] = *(const f16x8*)(rb + 8192 + pl * 8192 + offB0 + ni * 512);
    if (jstage < KT) stage(wb, jstage, 0);
    __builtin_amdgcn_s_setprio(1);
#pragma unroll
    for (int ni = 0; ni < 2; ++ni)
#pragma unroll
      for (int mi = 0; mi < 2; ++mi) {
        acc[mi][ni] = __builtin_amdgcn_mfma_f32_32x32x16_f16(a[mi][0], b[ni][0], acc[mi][ni], 0, 0, 0);
        acc[mi][ni] = __builtin_amdgcn_mfma_f32_32x32x16_f16(a[mi][0], b[ni][1], acc[mi][ni], 0, 0, 0);
        acc[mi][ni] = __builtin_amdgcn_mfma_f32_32x32x16_f16(a[mi][1], b[ni][0], acc[mi][ni], 0, 0, 0);
      }
    __builtin_amdgcn_s_setprio(0);
    // ---- phase 1: B frags ni={2,3}; stage half 1; 12 MFMA ----
#pragma unroll
    for (int ni = 0; ni < 2; ++ni)
#pragma unroll
      for (int pl = 0; pl < 2; ++pl)
        b[ni][pl] = *(const f16x8*)(rb + 8192 + pl * 8192 + offB0 + (ni + 2) * 512);
    if (jstage < KT) stage(wb, jstage, 1);
    __builtin_amdgcn_s_setprio(1);
#pragma unroll
    for (int ni = 0; ni < 2; ++ni)
#pragma unroll
      for (int mi = 0; mi < 2; ++mi) {
        acc[mi][ni + 2] = __builtin_amdgcn_mfma_f32_32x32x16_f16(a[mi][0], b[ni][0], acc[mi][ni + 2], 0, 0, 0);
        acc[mi][ni + 2] = __builtin_amdgcn_mfma_f32_32x32x16_f16(a[mi][0], b[ni][1], acc[mi][ni + 2], 0, 0, 0);
        acc[mi][ni + 2] = __builtin_amdgcn_mfma_f32_32x32x16_f16(a[mi][1], b[ni][0], acc[mi][ni + 2], 0, 0, 0);
      }
    __builtin_amdgcn_s_setprio(0);
  };

  auto kbar = [&](bool counted) {
    // counted: wait own oldest 6 loads (current tile), leave next tile's 6 in flight
    if (counted) asm volatile("s_waitcnt vmcnt(6)\n\ts_barrier" ::: "memory");
    else         asm volatile("s_waitcnt vmcnt(0)\n\ts_barrier" ::: "memory");
  };

  // prologue: tiles 0 and 1 fully issued (12 loads in flight)
  stage(smem[0], 0, 0); stage(smem[0], 0, 1);
  stage(smem[1], 1, 0); stage(smem[1], 1, 1);

  for (int j = 0; j < KT; j += 3) {
    kbar(j + 1 < KT); ktile(smem[0], smem[2], j + 2);
    kbar(j + 2 < KT); ktile(smem[1], smem[0], j + 3);
    kbar(j + 3 < KT); ktile(smem[2], smem[1], j + 4);
  }

  // ---- epilogue: per-row argmax over this wave's 128 cols, merge across wn ----
  float chv[4];
#pragma unroll
  for (int ni = 0; ni < 4; ++ni) chv[ni] = ch[nt * 256 + wn * 128 + ni * 32 + lo5];

#pragma unroll
  for (int mi = 0; mi < 2; ++mi)
#pragma unroll
    for (int q = 0; q < 16; ++q) {
      float v = acc[mi][0][q] - chv[0];
      int ix = nt * 256 + wn * 128 + lo5;
#pragma unroll
      for (int ni = 1; ni < 4; ++ni) {        // ni ascending => col ascending; strict >
        float s = acc[mi][ni][q] - chv[ni];
        if (s > v) { v = s; ix = nt * 256 + wn * 128 + ni * 32 + lo5; }
      }
#pragma unroll
      for (int m = 1; m <= 16; m <<= 1) {
        float ov = __shfl_xor(v, m, 64);
        int   oi = __shfl_xor(ix, m, 64);
        if (ov > v || (ov == v && oi < ix)) { v = ov; ix = oi; }
      }
      if (lo5 == 0) {
        int rr = (q & 3) + ((q >> 2) << 3) + (p << 2);   // C/D row within 32x32 tile
        int rloc = wm * 64 + mi * 32 + rr;               // 0..127
        red_v[wn][rloc] = v;
        red_i[wn][rloc] = ix;
      }
    }
  __syncthreads();
  if (tid < 128) {
    float v = red_v[0][tid];
    int ix = red_i[0][tid];
    float ov = red_v[1][tid];                  // wn=1 cols > wn=0 cols; strict > keeps first
    if (ov > v) { v = ov; ix = red_i[1][tid]; }
    int rowg = mt * 128 + tid;
    part[rowg * 4 + nt] = uint2{ __float_as_uint(v), (unsigned)ix };
  }
}

// ---------------- merge the 4 per-ntile candidates ----------------
__global__ void k_merge(const uint2* __restrict__ part, int* __restrict__ out) {
  int r = blockIdx.x * 256 + threadIdx.x;
  if (r >= MROWS) return;
  uint2 b0 = part[r * 4];
  float bvv = __uint_as_float(b0.x);
  int bii = (int)b0.y;
#pragma unroll
  for (int j = 1; j < 4; ++j) {
    uint2 pj = part[r * 4 + j];
    float v = __uint_as_float(pj.x);
    if (v > bvv) { bvv = v; bii = (int)pj.y; }   // nt ascending => idx ascending; strict >
  }
  out[r] = bii;
}

// ---------------- fallback (ws too small): fp32 wave-per-row ----------------
__global__ void k_naive(const float* __restrict__ E, const float* __restrict__ C,
                        int* __restrict__ out) {
  int row = blockIdx.x * 4 + (threadIdx.x >> 6);
  int lane = threadIdx.x & 63;
  const float* e = E + (size_t)row * KDIM;
  float bvv = -3.4e38f;
  int bii = 0;
  for (int c = 0; c < NCOLS; ++c) {
    const float* cc = C + (size_t)c * KDIM;
    float dot = 0.f, csq = 0.f;
    for (int d = lane; d < KDIM; d += 64) {
      float cv = cc[d];
      dot = fmaf(e[d], cv, dot);
      csq = fmaf(cv, cv, csq);
    }
#pragma unroll
    for (int m = 1; m < 64; m <<= 1) {
      dot += __shfl_xor(dot, m, 64);
      csq += __shfl_xor(csq, m, 64);
    }
    float s = dot - 0.5f * csq;
    if (s > bvv) { bvv = s; bii = c; }
  }
  if (lane == 0) out[row] = bii;
}

extern "C" void kernel_launch(void* const* d_in, const int* in_sizes, int n_in,
                              void* d_out, int out_size, void* d_ws, size_t ws_size,
                              hipStream_t stream) {
  const float* embed   = (const float*)d_in[0];
  const float* centers = (const float*)d_in[1];
  int* out = (int*)d_out;

  if (ws_size >= WS_NEED) {
    char* w = (char*)d_ws;
    _Float16* Aw = (_Float16*)w;
    _Float16* Bw = (_Float16*)(w + B_OFF);
    float*    ch = (float*)(w + CH_OFF);
    uint2*  partb = (uint2*)(w + PART_OFF);
    k_tile_A<<<188 * 48, 256, 0, stream>>>(embed, Aw);
    k_tile_B<<<4 * 48, 512, 0, stream>>>(centers, Bw);
    k_chalf<<<1024, 256, 0, stream>>>(centers, ch);
    k_gemm<<<752, 256, 0, stream>>>(Aw, Bw, ch, partb);
    k_merge<<<94, 256, 0, stream>>>(partb, out);
  } else {
    k_naive<<<6000, 256, 0, stream>>>(embed, centers, out);
  }
}

// Round 2
// 170.921 us; speedup vs baseline: 1.0491x; 1.0424x over previous
//
#include <hip/hip_runtime.h>
#include <cstdint>
#include <cstddef>

#define MROWS 24000
#define NCOLS 1024
#define KDIM  768
#define MT 188          // ceil(24000/128) m-tiles (padded to 24064 rows)
#define KT 48           // 768/16 k-tiles
#define NT 4            // 1024/256 n-tiles

typedef _Float16 f16x8  __attribute__((ext_vector_type(8)));
typedef float    f32x16 __attribute__((ext_vector_type(16)));

typedef __attribute__((address_space(1))) void as1_void;
typedef __attribute__((address_space(3))) void as3_void;

// ---- workspace layout (bytes) ----
#define A_BYTES   (188ull*48*8192)            // 73,924,608
#define B_OFF     A_BYTES
#define B_BYTES   (4ull*48*16384)             // 3,145,728
#define CH_OFF    (A_BYTES + B_BYTES)         // 77,070,336
#define PART_OFF  (CH_OFF + 4096)             // 77,074,432
#define WS_NEED   (PART_OFF + 24064ull*4*8)   // 77,844,480

// ---------------- conv A: embed -> tiled fp16 hi/lo ----------------
__global__ void k_tile_A(const float* __restrict__ E, _Float16* __restrict__ Aw) {
  int bid = blockIdx.x;            // mt*48 + kt
  int mt = bid / 48, kt = bid % 48;
  int t = threadIdx.x;             // 256
  int r = t >> 1, p = t & 1;
  int row = mt * 128 + r;
  __shared__ _Float16 lh[2][128][8];
  __shared__ _Float16 ll[2][128][8];
  float x[8];
  if (row < MROWS) {
    const float4* s4 = (const float4*)(E + (size_t)row * KDIM + kt * 16 + p * 8);
    float4 v0 = s4[0], v1 = s4[1];
    x[0]=v0.x; x[1]=v0.y; x[2]=v0.z; x[3]=v0.w; x[4]=v1.x; x[5]=v1.y; x[6]=v1.z; x[7]=v1.w;
  } else {
#pragma unroll
    for (int e = 0; e < 8; ++e) x[e] = 0.f;
  }
#pragma unroll
  for (int e = 0; e < 8; ++e) {
    _Float16 h = (_Float16)x[e];
    lh[p][r][e] = h;
    ll[p][r][e] = (_Float16)(x[e] - (float)h);
  }
  __syncthreads();
  const uint4* sh = (const uint4*)&lh[0][0][0];
  const uint4* sl = (const uint4*)&ll[0][0][0];
  uint4* dst = (uint4*)(Aw + (size_t)bid * 4096);   // 8192 B per tile
  dst[t]       = sh[t];    // h region: 256 chunks
  dst[256 + t] = sl[t];    // l region
}

// ---------------- conv B: centers -> tiled fp16 hi/lo ----------------
__global__ void k_tile_B(const float* __restrict__ C, _Float16* __restrict__ Bw) {
  int bid = blockIdx.x;            // nt*48 + kt
  int nt = bid / 48, kt = bid % 48;
  int t = threadIdx.x;             // 512
  int c = t >> 1, p = t & 1;
  __shared__ _Float16 lh[2][256][8];
  __shared__ _Float16 ll[2][256][8];
  const float4* s4 = (const float4*)(C + (size_t)(nt * 256 + c) * KDIM + kt * 16 + p * 8);
  float4 v0 = s4[0], v1 = s4[1];
  float x[8] = {v0.x, v0.y, v0.z, v0.w, v1.x, v1.y, v1.z, v1.w};
#pragma unroll
  for (int e = 0; e < 8; ++e) {
    _Float16 h = (_Float16)x[e];
    lh[p][c][e] = h;
    ll[p][c][e] = (_Float16)(x[e] - (float)h);
  }
  __syncthreads();
  const uint4* sh = (const uint4*)&lh[0][0][0];
  const uint4* sl = (const uint4*)&ll[0][0][0];
  uint4* dst = (uint4*)(Bw + (size_t)bid * 8192);   // 16384 B per tile
  dst[t]       = sh[t];    // h region: 512 chunks
  dst[512 + t] = sl[t];    // l region
}

// ---------------- 0.5*||c||^2 ----------------
__global__ void k_chalf(const float* __restrict__ C, float* __restrict__ ch) {
  int c = blockIdx.x, t = threadIdx.x;   // 256
  const float* src = C + (size_t)c * KDIM;
  float sq = 0.f;
#pragma unroll
  for (int i = 0; i < 3; ++i) {
    float x = src[t + i * 256];
    sq = fmaf(x, x, sq);
  }
#pragma unroll
  for (int m = 1; m < 64; m <<= 1) sq += __shfl_xor(sq, m, 64);
  __shared__ float part[4];
  if ((t & 63) == 0) part[t >> 6] = sq;
  __syncthreads();
  if (t == 0) ch[c] = 0.5f * ((part[0] + part[1]) + (part[2] + part[3]));
}

#define MFMA16(a, b, c) __builtin_amdgcn_mfma_f32_32x32x16_f16((a), (b), (c), 0, 0, 0)

// ---------------- fused GEMM: 8 waves, fine 2-phase/ktile, ring-3, counted vmcnt ----------------
// Block tile 128x256, 8 waves (2x4), wave tile 64x64, acc[2][2] 32x32 frags.
// Ring of 3 LDS buffers (24KB each). Tile j lives in buf j%3. During ktile j we
// issue tile j+2's 3 global_load_lds (each inst = 512 thr x 16B = 8KB) into the
// buffer freed at iter start. Entry barrier per ktile = s_waitcnt vmcnt(3);
// s_barrier -> tile j landed for all waves, tile j+1's 3 loads stay in flight.
// Per phase (m201 shape): ds_reads -> stage issue -> barrier -> setprio(1) ->
// MFMA cluster -> setprio(0) -> barrier.
__global__ __launch_bounds__(512, 4) void k_gemm(
    const _Float16* __restrict__ Aw, const _Float16* __restrict__ Bw,
    const float* __restrict__ ch, uint2* __restrict__ part) {
  __shared__ __align__(16) char smem[3][24576];   // per buf: [A-h 4K][A-l 4K][B-h 8K][B-l 8K]
  __shared__ float red_v[4][128];
  __shared__ int   red_i[4][128];

  const int bid0 = blockIdx.x;                  // 0..751
  const int swz = (bid0 & 7) * 94 + (bid0 >> 3);  // 752 = 8*94, bijective XCD swizzle
  const int nt = swz / MT, mt = swz % MT;

  const int tid = threadIdx.x, lane = tid & 63, wid = tid >> 6;  // 8 waves
  const int wm = wid >> 2, wn = wid & 3;        // 2x4 wave grid, wave tile 64x64
  const int lo5 = lane & 31, p = lane >> 5;

  const char* Ab = (const char*)Aw + (size_t)mt * (48 * 8192);
  const char* Bb = (const char*)Bw + (size_t)nt * (48 * 16384);

  // one stage inst = 512 threads x 16B = 8KB
  auto stageA = [&](char* sb, int kt) {
    __builtin_amdgcn_global_load_lds((as1_void*)(Ab + kt * 8192 + tid * 16),
                                     (as3_void*)(sb + tid * 16), 16, 0, 0);
  };
  auto stageB0 = [&](char* sb, int kt) {
    __builtin_amdgcn_global_load_lds((as1_void*)(Bb + kt * 16384 + tid * 16),
                                     (as3_void*)(sb + 8192 + tid * 16), 16, 0, 0);
  };
  auto stageB1 = [&](char* sb, int kt) {
    __builtin_amdgcn_global_load_lds((as1_void*)(Bb + kt * 16384 + 8192 + tid * 16),
                                     (as3_void*)(sb + 16384 + tid * 16), 16, 0, 0);
  };

  f32x16 acc[2][2] = {};
  const int offA = p * 2048 + (wm * 64 + lo5) * 16;   // + mi*512
  const int offB = p * 4096 + (wn * 64 + lo5) * 16;   // + ni*512

  char* rb = smem[0];   // tile j
  char* nb = smem[1];   // tile j+1 (in flight / landed)
  char* wb = smem[2];   // tile j+2 target

  stageA(smem[0], 0); stageB0(smem[0], 0); stageB1(smem[0], 0);
  stageA(smem[1], 1); stageB0(smem[1], 1); stageB1(smem[1], 1);

  for (int j = 0; j < KT; ++j) {
    // tile j landed (own 3 oldest); leave tile j+1's 3 in flight
    if (j < KT - 1) asm volatile("s_waitcnt vmcnt(3)" ::: "memory");
    else            asm volatile("s_waitcnt vmcnt(0)" ::: "memory");
    __builtin_amdgcn_s_barrier();

    // ---- phase 0: frags for ni=0 (+ all A); stage A + B0 of tile j+2 ----
    f16x8 ah0 = *(const f16x8*)(rb + offA);
    f16x8 ah1 = *(const f16x8*)(rb + offA + 512);
    f16x8 al0 = *(const f16x8*)(rb + 4096 + offA);
    f16x8 al1 = *(const f16x8*)(rb + 4096 + offA + 512);
    f16x8 bh0 = *(const f16x8*)(rb + 8192 + offB);
    f16x8 bl0 = *(const f16x8*)(rb + 16384 + offB);
    if (j + 2 < KT) { stageA(wb, j + 2); stageB0(wb, j + 2); }
    __builtin_amdgcn_s_barrier();
    __builtin_amdgcn_s_setprio(1);
    acc[0][0] = MFMA16(ah0, bh0, acc[0][0]);   // per-acc chain order: hh, h*bl, al*bh
    acc[0][0] = MFMA16(ah0, bl0, acc[0][0]);
    acc[0][0] = MFMA16(al0, bh0, acc[0][0]);
    acc[1][0] = MFMA16(ah1, bh0, acc[1][0]);
    acc[1][0] = MFMA16(ah1, bl0, acc[1][0]);
    acc[1][0] = MFMA16(al1, bh0, acc[1][0]);
    __builtin_amdgcn_s_setprio(0);
    __builtin_amdgcn_s_barrier();

    // ---- phase 1: frags for ni=1; stage B1 of tile j+2 ----
    f16x8 bh1 = *(const f16x8*)(rb + 8192 + offB + 512);
    f16x8 bl1 = *(const f16x8*)(rb + 16384 + offB + 512);
    if (j + 2 < KT) stageB1(wb, j + 2);
    __builtin_amdgcn_s_barrier();
    __builtin_amdgcn_s_setprio(1);
    acc[0][1] = MFMA16(ah0, bh1, acc[0][1]);
    acc[0][1] = MFMA16(ah0, bl1, acc[0][1]);
    acc[0][1] = MFMA16(al0, bh1, acc[0][1]);
    acc[1][1] = MFMA16(ah1, bh1, acc[1][1]);
    acc[1][1] = MFMA16(ah1, bl1, acc[1][1]);
    acc[1][1] = MFMA16(al1, bh1, acc[1][1]);
    __builtin_amdgcn_s_setprio(0);

    char* t = rb; rb = nb; nb = wb; wb = t;   // rotate ring
  }

  // ---- epilogue: per-row argmax over this wave's 64 cols, then merge across wn ----
  int c0 = nt * 256 + wn * 64 + lo5;
  int c1 = c0 + 32;
  float ch0 = ch[c0];
  float ch1 = ch[c1];
#pragma unroll
  for (int mi = 0; mi < 2; ++mi)
#pragma unroll
    for (int q = 0; q < 16; ++q) {
      float s0 = acc[mi][0][q] - ch0;
      float s1 = acc[mi][1][q] - ch1;
      float v = s0; int ix = c0;
      if (s1 > v) { v = s1; ix = c1; }   // c1 > c0: strict > keeps first index on ties
#pragma unroll
      for (int m = 1; m <= 16; m <<= 1) {
        float ov = __shfl_xor(v, m, 64);
        int   oi = __shfl_xor(ix, m, 64);
        if (ov > v || (ov == v && oi < ix)) { v = ov; ix = oi; }
      }
      if (lo5 == 0) {
        int rr = (q & 3) + ((q >> 2) << 3) + (p << 2);   // C/D row within 32x32 tile
        int rloc = wm * 64 + mi * 32 + rr;               // 0..127, unique per (wm,mi,q,p)
        red_v[wn][rloc] = v;
        red_i[wn][rloc] = ix;
      }
    }
  __syncthreads();
  if (tid < 128) {
    float v = red_v[0][tid];
    int ix = red_i[0][tid];
#pragma unroll
    for (int w = 1; w < 4; ++w) {       // wn ascending => col ascending; strict > keeps first
      float ov = red_v[w][tid];
      int oi = red_i[w][tid];
      if (ov > v) { v = ov; ix = oi; }
    }
    int rowg = mt * 128 + tid;
    part[rowg * 4 + nt] = uint2{ __float_as_uint(v), (unsigned)ix };
  }
}

// ---------------- merge the 4 per-ntile candidates ----------------
__global__ void k_merge(const uint2* __restrict__ part, int* __restrict__ out) {
  int r = blockIdx.x * 256 + threadIdx.x;
  if (r >= MROWS) return;
  uint2 b0 = part[r * 4];
  float bvv = __uint_as_float(b0.x);
  int bii = (int)b0.y;
#pragma unroll
  for (int j = 1; j < 4; ++j) {
    uint2 pj = part[r * 4 + j];
    float v = __uint_as_float(pj.x);
    if (v > bvv) { bvv = v; bii = (int)pj.y; }   // nt ascending => idx ascending; strict >
  }
  out[r] = bii;
}

// ---------------- fallback (ws too small): fp32 wave-per-row ----------------
__global__ void k_naive(const float* __restrict__ E, const float* __restrict__ C,
                        int* __restrict__ out) {
  int row = blockIdx.x * 4 + (threadIdx.x >> 6);
  int lane = threadIdx.x & 63;
  const float* e = E + (size_t)row * KDIM;
  float bvv = -3.4e38f;
  int bii = 0;
  for (int c = 0; c < NCOLS; ++c) {
    const float* cc = C + (size_t)c * KDIM;
    float dot = 0.f, csq = 0.f;
    for (int d = lane; d < KDIM; d += 64) {
      float cv = cc[d];
      dot = fmaf(e[d], cv, dot);
      csq = fmaf(cv, cv, csq);
    }
#pragma unroll
    for (int m = 1; m < 64; m <<= 1) {
      dot += __shfl_xor(dot, m, 64);
      csq += __shfl_xor(csq, m, 64);
    }
    float s = dot - 0.5f * csq;
    if (s > bvv) { bvv = s; bii = c; }
  }
  if (lane == 0) out[row] = bii;
}

extern "C" void kernel_launch(void* const* d_in, const int* in_sizes, int n_in,
                              void* d_out, int out_size, void* d_ws, size_t ws_size,
                              hipStream_t stream) {
  const float* embed   = (const float*)d_in[0];
  const float* centers = (const float*)d_in[1];
  int* out = (int*)d_out;

  if (ws_size >= WS_NEED) {
    char* w = (char*)d_ws;
    _Float16* Aw = (_Float16*)w;
    _Float16* Bw = (_Float16*)(w + B_OFF);
    float*    ch = (float*)(w + CH_OFF);
    uint2*  partb = (uint2*)(w + PART_OFF);
    k_tile_A<<<188 * 48, 256, 0, stream>>>(embed, Aw);
    k_tile_B<<<4 * 48, 512, 0, stream>>>(centers, Bw);
    k_chalf<<<1024, 256, 0, stream>>>(centers, ch);
    k_gemm<<<752, 512, 0, stream>>>(Aw, Bw, ch, partb);
    k_merge<<<94, 256, 0, stream>>>(partb, out);
  } else {
    k_naive<<<6000, 256, 0, stream>>>(embed, centers, out);
  }
}